// Round 6
// baseline (213.682 us; speedup 1.0000x reference)
//
#include <hip/hip_runtime.h>

// ---------------------------------------------------------------------------
// VM-LSTM cell, B=8192, D=H=1024, G=2, WR=64, URANKS=[64,64]
//
//   prep  : stage-1 weights MFMA-frag-major fp16 (U1f, Uh1f); stage-2 W2f
//           frag-major fp16; correction vectors cx/ch/bb (wave-parallel).
//   fused : s1+s2 in ONE kernel. r6: 16 rows/block, 512 thr (8 waves),
//           grid 512 = 2 blocks/CU (LDS 76.5 KB <= 80 KB) so block n+1's
//           Phase A/B overlaps block n's Phase C on the same CU (r5 was
//           1 block/CU at 153 KB: phases serialized, 77.5 us, Occ 42%).
//           Phase A: stage x,h -> fp16 LDS (nontemporal ext-vector loads).
//           Phase B: stage-1 MFMAs -> T=[X|P0|P1|P2|P3] (16x320) in LDS.
//             waves 0-3: X-tile ct=w (32 MFMA) + P-tile w (16); waves 4-7:
//             3 P-tiles (48) — balanced.
//           Phase C: barrier-free stage-2: 8 col-tiles/wave, acc[4];
//             A-frags from LDS in-loop; B-frags from W2f (L2-hot, batched);
//             c prefetched 1 tile ahead (nontemporal); plain out stores.
// Gates: q=0 i, 1 f (secIF); 2 o, 3 n (secON). W2f layout unchanged.
// ---------------------------------------------------------------------------

typedef _Float16 half8 __attribute__((ext_vector_type(8)));
typedef _Float16 half4v __attribute__((ext_vector_type(4)));
typedef float f32x4 __attribute__((ext_vector_type(4)));

// workspace offsets (bytes)
#define WS_U1F   0                     // 131072 B
#define WS_UH1F  131072                // 262144 B
#define WS_W2    393216                // 1572864 B (frag-major)
#define WS_CX    1966080               // 4096 fp32
#define WS_CH    1982464
#define WS_BB    1998848

// ---------------------------------------------------------------------------
__global__ __launch_bounds__(256) void prep_kernel(
    const float* __restrict__ Ux, const float* __restrict__ Vx,
    const float* __restrict__ Uh0, const float* __restrict__ Vh0,
    const float* __restrict__ Uh1, const float* __restrict__ Vh1,
    const float* __restrict__ dia_x, const float* __restrict__ dia_h,
    const float* __restrict__ bias_x, const float* __restrict__ bias_h,
    _Float16* __restrict__ U1f, _Float16* __restrict__ Uh1f,
    _Float16* __restrict__ W2f, float* __restrict__ cx,
    float* __restrict__ ch, float* __restrict__ bb)
{
    int e = blockIdx.x * 256 + threadIdx.x;
    if (e < 8192) {
        // U1f[ct(4)][ks(32)][lane][8]: B-frag for x@Ux.
        int lane = e & 63, ks = (e >> 6) & 31, ct = e >> 11;
        int l15 = lane & 15, quad = lane >> 4;
        half8 v8;
        #pragma unroll
        for (int jj = 0; jj < 8; ++jj) {
            int k = ks * 32 + quad * 8 + jj;
            v8[jj] = (_Float16)Ux[k * 64 + ct * 16 + l15];
        }
        *(half8*)&U1f[(size_t)e * 8] = v8;
    } else if (e < 24576) {
        // Uh1f[j(4)][ct(4)][ks(16)][lane][8]; j: 0=Uh0g0,1=Uh1g0,2=Uh0g1,3=Uh1g1
        int t = e - 8192;
        int lane = t & 63, ks = (t >> 6) & 15, ct = (t >> 10) & 3, j = t >> 12;
        int l15 = lane & 15, quad = lane >> 4;
        const float* src = (j & 1) ? Uh1 : Uh0;
        int g = j >> 1;
        half8 v8;
        #pragma unroll
        for (int jj = 0; jj < 8; ++jj) {
            int k = ks * 32 + quad * 8 + jj;
            v8[jj] = (_Float16)src[(g * 512 + k) * 64 + ct * 16 + l15];
        }
        *(half8*)&Uh1f[(size_t)t * 8] = v8;
    } else if (e < 122880) {
        // W2f fragment-major: t = (((s*2+g01)*64 + ct)*6 + ks)*64 + lane
        int t = e - 24576;                 // 0..98303
        int lane = t & 63;
        int ksq  = (t >> 6) % 6;
        int ct   = (t / 384) & 63;
        int g01  = (t / 24576) & 1;
        int s    = t / 49152;
        int l15 = lane & 15, quad = lane >> 4;
        int k = ct * 16 + l15;             // output column
        int jx = s * 2 + g01;
        int m = (g01 == 0) ? (1024 + k) : k;
        half8 v8;
        #pragma unroll
        for (int jj = 0; jj < 8; ++jj) {
            int kk = ksq * 32 + quad * 8 + jj;   // K index 0..191
            int r = kk & 63, sect = kk >> 6;
            float val;
            if (sect == 0)      val = Vx[(jx * 1024 + k) * 64 + r];
            else if (sect == 1) val = Vh0[(s * 64 + r) * 2048 + m];
            else                val = Vh1[(s * 64 + r) * 2048 + m];
            v8[jj] = (_Float16)val;
        }
        *(half8*)&W2f[(size_t)t * 8] = v8;
    } else {
        // correction vectors, wave-parallel: one wave per element t, lane = r.
        int t64 = e - 122880;              // 0..262143
        int t = t64 >> 6;                  // 0..4095
        int r = t64 & 63;
        int q = t >> 10; int k = t & 1023;
        int jh = q ^ 1;
        int fh = jh * 1024 + k; int g = fh >> 11; int m = fh & 2047;
        float sx = Ux[k * 64 + r] * Vx[(q * 1024 + k) * 64 + r];
        float sh = Uh0[k * 64 + r] * Vh0[(g * 64 + r) * 2048 + m];
        #pragma unroll
        for (int d = 32; d > 0; d >>= 1) {
            sx += __shfl_xor(sx, d, 64);
            sh += __shfl_xor(sh, d, 64);
        }
        if (r == 0) {
            cx[t] = dia_x[k] - sx;
            ch[t] = dia_h[k] - sh;
            bb[t] = bias_x[q * 1024 + k] + bias_h[jh * 1024 + k];
        }
    }
}

// ---------------------------------------------------------------------------
__global__ __launch_bounds__(512, 4) void fused_kernel(
    const float* __restrict__ x, const float* __restrict__ h,
    const float* __restrict__ c,
    const _Float16* __restrict__ U1f, const _Float16* __restrict__ Uh1f,
    const _Float16* __restrict__ W2f,
    const float* __restrict__ cx, const float* __restrict__ ch,
    const float* __restrict__ bb, float* __restrict__ out)
{
    // pad rows by +8 fp16 (16B): keeps half8 alignment, breaks pow2 stride
    __shared__ __align__(16) _Float16 Xsh[16][1032];   // 33024 B
    __shared__ __align__(16) _Float16 Hsh[16][1032];   // 33024 B
    __shared__ __align__(16) _Float16 Tsh[16][328];    // 10496 B (total 76544)

    const int tid = threadIdx.x;
    const int w = tid >> 6, l = tid & 63, l15 = l & 15, quad = l >> 4;
    const int b0 = blockIdx.x * 16;
    const size_t rowbase = (size_t)b0 * 1024;

    // ---- Phase A: stage x,h -> fp16 LDS (16 rows x 1024 each) ----
    {
        const float* xs = x + rowbase;
        const float* hs = h + rowbase;
        #pragma unroll
        for (int ii = 0; ii < 8; ++ii) {
            int idx = tid + ii * 512;          // 0..4095 = 16 rows x 256 float4
            int row = idx >> 8, c4 = idx & 255;
            f32x4 fx = __builtin_nontemporal_load(
                (const f32x4*)&xs[(size_t)row * 1024 + c4 * 4]);
            f32x4 fh = __builtin_nontemporal_load(
                (const f32x4*)&hs[(size_t)row * 1024 + c4 * 4]);
            half4v px, ph;
            px[0] = (_Float16)fx[0]; px[1] = (_Float16)fx[1];
            px[2] = (_Float16)fx[2]; px[3] = (_Float16)fx[3];
            ph[0] = (_Float16)fh[0]; ph[1] = (_Float16)fh[1];
            ph[2] = (_Float16)fh[2]; ph[3] = (_Float16)fh[3];
            *(half4v*)&Xsh[row][c4 * 4] = px;
            *(half4v*)&Hsh[row][c4 * 4] = ph;
        }
    }
    __syncthreads();

    // ---- Phase B: stage-1 -> Tsh = [X(0) | P0(64) | P1(128) | P2(192) | P3(256)]
    if (w < 4) {
        // X-tile: out cols ct*16.., rows 0-15, K=1024 over Xsh
        int ct = w;
        f32x4 acc = {};
        const _Float16* bp = U1f + ((size_t)(ct * 32) * 64 + l) * 8;
        #pragma unroll
        for (int ks = 0; ks < 32; ++ks) {
            half8 a = *(const half8*)&Xsh[l15][ks * 32 + quad * 8];
            half8 b = *(const half8*)(bp + (size_t)ks * 512);
            acc = __builtin_amdgcn_mfma_f32_16x16x32_f16(a, b, acc, 0, 0, 0);
        }
        #pragma unroll
        for (int r = 0; r < 4; ++r)
            Tsh[quad * 4 + r][ct * 16 + l15] = (_Float16)acc[r];
    }
    {
        // P-tiles: p = j*4 + pct, 16 total (single row-tile).
        // waves 0-3: 1 tile (p=w, j=0); waves 4-7: 3 tiles (p=4..15).
        // A = Hsh half: j in {0,3} -> cols 0-511; j in {1,2} -> cols 512-1023
        int pstart = (w < 4) ? w : 4 + (w - 4) * 3;
        int pcnt   = (w < 4) ? 1 : 3;
        for (int ii = 0; ii < 3; ++ii) {
            if (ii >= pcnt) break;
            int p = pstart + ii;
            int j = p >> 2, pct = p & 3;
            int hoff = (j == 1 || j == 2) ? 512 : 0;
            f32x4 pa = {};
            const _Float16* pb = Uh1f + ((size_t)((j * 4 + pct) * 16) * 64 + l) * 8;
            #pragma unroll
            for (int ks = 0; ks < 16; ++ks) {
                half8 a = *(const half8*)&Hsh[l15][hoff + ks * 32 + quad * 8];
                half8 b = *(const half8*)(pb + (size_t)ks * 512);
                pa = __builtin_amdgcn_mfma_f32_16x16x32_f16(a, b, pa, 0, 0, 0);
            }
            #pragma unroll
            for (int r = 0; r < 4; ++r)
                Tsh[quad * 4 + r][64 + j * 64 + pct * 16 + l15] = (_Float16)pa[r];
        }
    }
    __syncthreads();

    // ---- Phase C: stage-2, barrier-free. 8 col-tiles per wave; A-frags
    //      from LDS in-loop; B-frags from W2f with loads batched in flight.
    const int secIF[3] = {0, 64, 128};     // gates i,f  = [X | P0 | P1]
    const int secON[3] = {0, 192, 256};    // gates o,n  = [X | P2 | P3]

    // c prefetch double-buffer (static indices after full unroll)
    float cpref[2][4];
    {
        int k0 = w * 16 + l15;             // tile i=0: ctg = w
        #pragma unroll
        for (int r = 0; r < 4; ++r)
            cpref[0][r] = __builtin_nontemporal_load(
                &c[rowbase + (size_t)(quad * 4 + r) * 1024 + k0]);
    }

    #pragma unroll
    for (int i = 0; i < 8; ++i) {
        const int ctg = w + 8 * i;         // col-tile 0..63, disjoint across waves
        const int k = ctg * 16 + l15;

        // prefetch c for next tile
        if (i < 7) {
            int kn = k + 128;
            #pragma unroll
            for (int r = 0; r < 4; ++r)
                cpref[(i + 1) & 1][r] = __builtin_nontemporal_load(
                    &c[rowbase + (size_t)(quad * 4 + r) * 1024 + kn]);
        }

        // correction scalars (L2-hot, issued before MFMA loop)
        float cxi = cx[k], cxf = cx[1024 + k], cxo = cx[2048 + k], cxn = cx[3072 + k];
        float chi = ch[k], chf = ch[1024 + k], cho = ch[2048 + k], chn = ch[3072 + k];
        float bbi = bb[k], bbf = bb[1024 + k], bbo = bb[2048 + k], bbn = bb[3072 + k];

        const size_t laneoff = (size_t)l * 8;
        const _Float16* bpi = W2f + (size_t)((0 * 64 + ctg) * 6) * 512 + laneoff;
        const _Float16* bpf = W2f + (size_t)((1 * 64 + ctg) * 6) * 512 + laneoff;
        const _Float16* bpo = W2f + (size_t)((2 * 64 + ctg) * 6) * 512 + laneoff;
        const _Float16* bpn = W2f + (size_t)((3 * 64 + ctg) * 6) * 512 + laneoff;

        f32x4 acc[4] = {};                 // [gate]
        #pragma unroll
        for (int ks = 0; ks < 6; ++ks) {
            half8 bi = *(const half8*)(bpi + (size_t)ks * 512);
            half8 bf = *(const half8*)(bpf + (size_t)ks * 512);
            half8 bo = *(const half8*)(bpo + (size_t)ks * 512);
            half8 bn = *(const half8*)(bpn + (size_t)ks * 512);
            int coff = (ks & 1) * 32 + quad * 8;
            half8 aA = *(const half8*)&Tsh[l15][secIF[ks >> 1] + coff];
            half8 aB = *(const half8*)&Tsh[l15][secON[ks >> 1] + coff];
            acc[0] = __builtin_amdgcn_mfma_f32_16x16x32_f16(aA, bi, acc[0], 0, 0, 0);
            acc[1] = __builtin_amdgcn_mfma_f32_16x16x32_f16(aA, bf, acc[1], 0, 0, 0);
            acc[2] = __builtin_amdgcn_mfma_f32_16x16x32_f16(aB, bo, acc[2], 0, 0, 0);
            acc[3] = __builtin_amdgcn_mfma_f32_16x16x32_f16(aB, bn, acc[3], 0, 0, 0);
        }

        // epilogue: corrections from fp16 LDS x/h; c from prefetch regs
        #pragma unroll
        for (int r = 0; r < 4; ++r) {
            int rl = quad * 4 + r;
            size_t off = rowbase + (size_t)rl * 1024 + k;
            float xv = (float)Xsh[rl][k];
            float hv = (float)Hsh[rl][k];
            float cvv = cpref[i & 1][r];
            float pi = acc[0][r] + xv * cxi + hv * chi + bbi;
            float pf = acc[1][r] + xv * cxf + hv * chf + bbf;
            float po = acc[2][r] + xv * cxo + hv * cho + bbo;
            float pn = acc[3][r] + xv * cxn + hv * chn + bbn;
            float ig = __builtin_amdgcn_rcpf(1.f + __expf(-pi));
            float fg = __builtin_amdgcn_rcpf(1.f + __expf(-pf));
            float og = __builtin_amdgcn_rcpf(1.f + __expf(-po));
            float ng = 1.f - 2.f * __builtin_amdgcn_rcpf(__expf(2.f * pn) + 1.f);
            float cn = fg * cvv + ig * ng;
            float tc = 1.f - 2.f * __builtin_amdgcn_rcpf(__expf(2.f * cn) + 1.f);
            out[off] = og * tc;
            out[(size_t)8388608 + off] = cn;
        }
    }
}

// ---------------------------------------------------------------------------
extern "C" void kernel_launch(void* const* d_in, const int* in_sizes, int n_in,
                              void* d_out, int out_size, void* d_ws, size_t ws_size,
                              hipStream_t stream)
{
    const float* x      = (const float*)d_in[0];
    const float* h      = (const float*)d_in[1];
    const float* c      = (const float*)d_in[2];
    const float* dia_x  = (const float*)d_in[3];
    const float* dia_h  = (const float*)d_in[4];
    const float* Ux     = (const float*)d_in[5];
    const float* Vx     = (const float*)d_in[6];
    const float* Uh0    = (const float*)d_in[7];
    const float* Vh0    = (const float*)d_in[8];
    const float* Uh1    = (const float*)d_in[9];
    const float* Vh1    = (const float*)d_in[10];
    const float* bias_x = (const float*)d_in[11];
    const float* bias_h = (const float*)d_in[12];
    float* out = (float*)d_out;

    char* ws = (char*)d_ws;
    _Float16* U1f  = (_Float16*)(ws + WS_U1F);
    _Float16* Uh1f = (_Float16*)(ws + WS_UH1F);
    _Float16* W2f  = (_Float16*)(ws + WS_W2);
    float* cx = (float*)(ws + WS_CX);
    float* ch = (float*)(ws + WS_CH);
    float* bb = (float*)(ws + WS_BB);

    // 8192 + 16384 + 98304 + 262144 = 385024 threads = 1504 blocks
    prep_kernel<<<1504, 256, 0, stream>>>(Ux, Vx, Uh0, Vh0, Uh1, Vh1,
                                          dia_x, dia_h, bias_x, bias_h,
                                          U1f, Uh1f, W2f, cx, ch, bb);
    fused_kernel<<<512, 512, 0, stream>>>(x, h, c, U1f, Uh1f, W2f,
                                          cx, ch, bb, out);
}

// Round 7
// 207.973 us; speedup vs baseline: 1.0275x; 1.0275x over previous
//
#include <hip/hip_runtime.h>

// ---------------------------------------------------------------------------
// VM-LSTM cell, B=8192, D=H=1024, G=2, WR=64, URANKS=[64,64]
//
//   prep v2: r6 discovery — prep was ~100 us (total-minus-fused residue),
//           dominated by 8KB-stride scatter reads of Vh0/Vh1 (each v8 elem
//           on its own cache line). Fix:
//             * Vh->W2f via LDS transpose blocks (coalesced float4 loads,
//               [64][260] fp16 tile, coalesced half8 frag stores)
//             * corrections: lane=t (coalesced Vh read), serial r-loop
//             * Vx->W2f part keeps old (line-efficient) indexing
//   fused : r5 version verbatim (measured best 77.5 us): 32 rows/block,
//           1024 thr (16 waves), grid 256, 1 block/CU. r6's 2-blocks/CU
//           experiment was neutral-negative (79.5) — reverted.
// Gates: q=0 i, 1 f (secIF); 2 o, 3 n (secON). W2f layout unchanged.
// ---------------------------------------------------------------------------

typedef _Float16 half8 __attribute__((ext_vector_type(8)));
typedef _Float16 half4v __attribute__((ext_vector_type(4)));
typedef float f32x4 __attribute__((ext_vector_type(4)));

// workspace offsets (bytes)
#define WS_U1F   0                     // 131072 B
#define WS_UH1F  131072                // 262144 B
#define WS_W2    393216                // 1572864 B (frag-major)
#define WS_CX    1966080               // 4096 fp32
#define WS_CH    1982464
#define WS_BB    1998848

// ---------------------------------------------------------------------------
// prep v2 thread map (grid 272 x 256):
//   e in [0,8192)        : U1f
//   e in [8192,24576)    : Uh1f
//   e in [24576,57344)   : W2f Vx part (ksq 0,1)
//   e in [57344,61440)   : corrections (lane = t, r-loop)
//   blocks 240..271      : W2f Vh transpose (s,i,mchunk), LDS tile
__global__ __launch_bounds__(256) void prep_kernel(
    const float* __restrict__ Ux, const float* __restrict__ Vx,
    const float* __restrict__ Uh0, const float* __restrict__ Vh0,
    const float* __restrict__ Uh1, const float* __restrict__ Vh1,
    const float* __restrict__ dia_x, const float* __restrict__ dia_h,
    const float* __restrict__ bias_x, const float* __restrict__ bias_h,
    _Float16* __restrict__ U1f, _Float16* __restrict__ Uh1f,
    _Float16* __restrict__ W2f, float* __restrict__ cx,
    float* __restrict__ ch, float* __restrict__ bb)
{
    __shared__ __align__(16) _Float16 Tl[64][260];   // 33280 B transpose tile

    const int tid = threadIdx.x;
    if (blockIdx.x >= 240) {
        // ---- Vh -> W2f frag-major via LDS transpose ----
        int bid2 = blockIdx.x - 240;       // 0..31
        int s = bid2 & 1, i = (bid2 >> 1) & 1, mchunk = bid2 >> 2;
        const float* Vh = i ? Vh1 : Vh0;
        // load 64 r x 256 m fp32 coalesced -> fp16 LDS [r][m]
        #pragma unroll
        for (int it = 0; it < 16; ++it) {
            int idx = tid + it * 256;      // 0..4095 = 64 rows x 64 float4
            int row = idx >> 6, c4 = idx & 63;
            f32x4 v = *(const f32x4*)&Vh[(size_t)(s * 64 + row) * 2048
                                         + mchunk * 256 + c4 * 4];
            half4v p;
            p[0] = (_Float16)v[0]; p[1] = (_Float16)v[1];
            p[2] = (_Float16)v[2]; p[3] = (_Float16)v[3];
            *(half4v*)&Tl[row][c4 * 4] = p;
        }
        __syncthreads();
        // emit frags: 32 combos (ct_local x rk) x 64 lanes; coalesced stores
        int lane = tid & 63, l15 = lane & 15, quad = lane >> 4;
        #pragma unroll
        for (int q = 0; q < 8; ++q) {
            int combo = (tid >> 6) * 8 + q;        // 0..31
            int ct_local = combo >> 1, rk = combo & 1;
            int m_local = ct_local * 16 + l15;
            int m = mchunk * 256 + m_local;
            int g01 = (m >= 1024) ? 0 : 1;
            int ct_global = (m - (1 - g01) * 1024) >> 4;
            int ksq = 2 + 2 * i + rk;
            half8 v8;
            #pragma unroll
            for (int jj = 0; jj < 8; ++jj)
                v8[jj] = Tl[rk * 32 + quad * 8 + jj][m_local];
            size_t t_out = (((size_t)(s * 2 + g01) * 64 + ct_global) * 6 + ksq) * 64 + lane;
            *(half8*)&W2f[t_out * 8] = v8;
        }
        return;
    }

    int e = blockIdx.x * 256 + tid;
    if (e < 8192) {
        // U1f[ct(4)][ks(32)][lane][8]: B-frag for x@Ux.
        int lane = e & 63, ks = (e >> 6) & 31, ct = e >> 11;
        int l15 = lane & 15, quad = lane >> 4;
        half8 v8;
        #pragma unroll
        for (int jj = 0; jj < 8; ++jj) {
            int k = ks * 32 + quad * 8 + jj;
            v8[jj] = (_Float16)Ux[k * 64 + ct * 16 + l15];
        }
        *(half8*)&U1f[(size_t)e * 8] = v8;
    } else if (e < 24576) {
        // Uh1f[j(4)][ct(4)][ks(16)][lane][8]; j: 0=Uh0g0,1=Uh1g0,2=Uh0g1,3=Uh1g1
        int t = e - 8192;
        int lane = t & 63, ks = (t >> 6) & 15, ct = (t >> 10) & 3, j = t >> 12;
        int l15 = lane & 15, quad = lane >> 4;
        const float* src = (j & 1) ? Uh1 : Uh0;
        int g = j >> 1;
        half8 v8;
        #pragma unroll
        for (int jj = 0; jj < 8; ++jj) {
            int k = ks * 32 + quad * 8 + jj;
            v8[jj] = (_Float16)src[(g * 512 + k) * 64 + ct * 16 + l15];
        }
        *(half8*)&Uh1f[(size_t)t * 8] = v8;
    } else if (e < 57344) {
        // W2f Vx part: ksq in {0,1}; tt = (((s*2+g01)*64+ct)*2 + ksq2)*64+lane
        int tt = e - 24576;                // 0..32767
        int lane = tt & 63;
        int ksq2 = (tt >> 6) & 1;
        int ct   = (tt / 128) & 63;
        int g01  = (tt / 8192) & 1;
        int s    = tt / 16384;
        int l15 = lane & 15, quad = lane >> 4;
        int k = ct * 16 + l15;
        int jx = s * 2 + g01;
        half8 v8;
        #pragma unroll
        for (int jj = 0; jj < 8; ++jj) {
            int r = ksq2 * 32 + quad * 8 + jj;     // 0..63
            v8[jj] = (_Float16)Vx[(jx * 1024 + k) * 64 + r];
        }
        size_t t_out = (((size_t)(s * 2 + g01) * 64 + ct) * 6 + ksq2) * 64 + lane;
        *(half8*)&W2f[t_out * 8] = v8;
    } else if (e < 61440) {
        // corrections: one thread per t; lanes span k -> Vh read coalesced.
        int t = e - 57344;                 // 0..4095
        int q = t >> 10; int k = t & 1023;
        int jh = q ^ 1;
        int fh = jh * 1024 + k; int g = fh >> 11; int m = fh & 2047;
        float sx0 = 0.f, sx1 = 0.f, sh0 = 0.f, sh1 = 0.f;
        #pragma unroll 4
        for (int r = 0; r < 64; r += 2) {
            sx0 += Ux[k * 64 + r]     * Vx[(q * 1024 + k) * 64 + r];
            sx1 += Ux[k * 64 + r + 1] * Vx[(q * 1024 + k) * 64 + r + 1];
            sh0 += Uh0[k * 64 + r]     * Vh0[(size_t)(g * 64 + r) * 2048 + m];
            sh1 += Uh0[k * 64 + r + 1] * Vh0[(size_t)(g * 64 + r + 1) * 2048 + m];
        }
        cx[t] = dia_x[k] - (sx0 + sx1);
        ch[t] = dia_h[k] - (sh0 + sh1);
        bb[t] = bias_x[q * 1024 + k] + bias_h[jh * 1024 + k];
    }
}

// ---------------------------------------------------------------------------
__global__ __launch_bounds__(1024) void fused_kernel(
    const float* __restrict__ x, const float* __restrict__ h,
    const float* __restrict__ c,
    const _Float16* __restrict__ U1f, const _Float16* __restrict__ Uh1f,
    const _Float16* __restrict__ W2f,
    const float* __restrict__ cx, const float* __restrict__ ch,
    const float* __restrict__ bb, float* __restrict__ out)
{
    // pad rows by +8 fp16 (16B): keeps half8 alignment, breaks pow2 stride
    __shared__ __align__(16) _Float16 Xsh[32][1032];   // 66048 B
    __shared__ __align__(16) _Float16 Hsh[32][1032];   // 66048 B
    __shared__ __align__(16) _Float16 Tsh[32][328];    // 20992 B  (total 153088)

    const int tid = threadIdx.x;
    const int w = tid >> 6, l = tid & 63, l15 = l & 15, quad = l >> 4;
    const int b0 = blockIdx.x * 32;
    const size_t rowbase = (size_t)b0 * 1024;

    // ---- Phase A: stage x,h -> fp16 LDS (32 rows x 1024 each) ----
    {
        const float* xs = x + rowbase;
        const float* hs = h + rowbase;
        #pragma unroll
        for (int ii = 0; ii < 8; ++ii) {
            int idx = tid + ii * 1024;         // 0..8191 = 32 rows x 256 float4
            int row = idx >> 8, c4 = idx & 255;
            f32x4 fx = __builtin_nontemporal_load(
                (const f32x4*)&xs[(size_t)row * 1024 + c4 * 4]);
            f32x4 fh = __builtin_nontemporal_load(
                (const f32x4*)&hs[(size_t)row * 1024 + c4 * 4]);
            half4v px, ph;
            px[0] = (_Float16)fx[0]; px[1] = (_Float16)fx[1];
            px[2] = (_Float16)fx[2]; px[3] = (_Float16)fx[3];
            ph[0] = (_Float16)fh[0]; ph[1] = (_Float16)fh[1];
            ph[2] = (_Float16)fh[2]; ph[3] = (_Float16)fh[3];
            *(half4v*)&Xsh[row][c4 * 4] = px;
            *(half4v*)&Hsh[row][c4 * 4] = ph;
        }
    }
    __syncthreads();

    // ---- Phase B: stage-1 -> Tsh = [X(0) | P0(64) | P1(128) | P2(192) | P3(256)]
    if (w < 8) {
        // X-tile: out cols ct*16.., rows rt*16.., K=1024 over Xsh
        int rt = w & 1, ct = w >> 1;
        f32x4 acc = {};
        const _Float16* bp = U1f + ((size_t)(ct * 32) * 64 + l) * 8;
        #pragma unroll
        for (int ks = 0; ks < 32; ++ks) {
            half8 a = *(const half8*)&Xsh[rt * 16 + l15][ks * 32 + quad * 8];
            half8 b = *(const half8*)(bp + (size_t)ks * 512);
            acc = __builtin_amdgcn_mfma_f32_16x16x32_f16(a, b, acc, 0, 0, 0);
        }
        #pragma unroll
        for (int r = 0; r < 4; ++r)
            Tsh[rt * 16 + quad * 4 + r][ct * 16 + l15] = (_Float16)acc[r];
    }
    {
        // P-tiles: p = j*8 + prt*4 + pct, j = which h-matrix, 32 total.
        // waves 0-7: 1 tile (p=w, all j=0); waves 8-15: 3 tiles (p=8..31).
        // A = Hsh half: j in {0,3} -> cols 0-511; j in {1,2} -> cols 512-1023
        int pstart = (w < 8) ? w : 8 + (w - 8) * 3;
        int pcnt   = (w < 8) ? 1 : 3;
        for (int ii = 0; ii < 3; ++ii) {
            if (ii >= pcnt) break;
            int p = pstart + ii;
            int j = p >> 3, rem = p & 7, prt = rem >> 2, pct = rem & 3;
            int hoff = (j == 1 || j == 2) ? 512 : 0;
            f32x4 pa = {};
            const _Float16* pb = Uh1f + ((size_t)((j * 4 + pct) * 16) * 64 + l) * 8;
            #pragma unroll
            for (int ks = 0; ks < 16; ++ks) {
                half8 a = *(const half8*)&Hsh[prt * 16 + l15][hoff + ks * 32 + quad * 8];
                half8 b = *(const half8*)(pb + (size_t)ks * 512);
                pa = __builtin_amdgcn_mfma_f32_16x16x32_f16(a, b, pa, 0, 0, 0);
            }
            #pragma unroll
            for (int r = 0; r < 4; ++r)
                Tsh[prt * 16 + quad * 4 + r][64 + j * 64 + pct * 16 + l15] = (_Float16)pa[r];
        }
    }
    __syncthreads();

    // ---- Phase C: stage-2, barrier-free. 4 col-tiles per wave; A-frags
    //      from LDS in-loop; B-frags from W2f with loads batched in flight.
    const int secIF[3] = {0, 64, 128};     // gates i,f  = [X | P0 | P1]
    const int secON[3] = {0, 192, 256};    // gates o,n  = [X | P2 | P3]

    // c prefetch double-buffer (static indices after full unroll)
    float cpref[2][2][4];
    {
        int k0 = w * 16 + l15;             // tile i=0: ctg = w
        #pragma unroll
        for (int rt = 0; rt < 2; ++rt)
            #pragma unroll
            for (int r = 0; r < 4; ++r)
                cpref[0][rt][r] = __builtin_nontemporal_load(
                    &c[rowbase + (size_t)(rt * 16 + quad * 4 + r) * 1024 + k0]);
    }

    #pragma unroll
    for (int i = 0; i < 4; ++i) {
        const int ctg = w + 16 * i;        // col-tile 0..63, disjoint across waves
        const int k = ctg * 16 + l15;

        // prefetch c for next tile
        if (i < 3) {
            int kn = k + 256;
            #pragma unroll
            for (int rt = 0; rt < 2; ++rt)
                #pragma unroll
                for (int r = 0; r < 4; ++r)
                    cpref[(i + 1) & 1][rt][r] = __builtin_nontemporal_load(
                        &c[rowbase + (size_t)(rt * 16 + quad * 4 + r) * 1024 + kn]);
        }

        // correction scalars (L2-hot, issued before MFMA loop)
        float cxi = cx[k], cxf = cx[1024 + k], cxo = cx[2048 + k], cxn = cx[3072 + k];
        float chi = ch[k], chf = ch[1024 + k], cho = ch[2048 + k], chn = ch[3072 + k];
        float bbi = bb[k], bbf = bb[1024 + k], bbo = bb[2048 + k], bbn = bb[3072 + k];

        const size_t laneoff = (size_t)l * 8;
        const _Float16* bpi = W2f + (size_t)((0 * 64 + ctg) * 6) * 512 + laneoff;
        const _Float16* bpf = W2f + (size_t)((1 * 64 + ctg) * 6) * 512 + laneoff;
        const _Float16* bpo = W2f + (size_t)((2 * 64 + ctg) * 6) * 512 + laneoff;
        const _Float16* bpn = W2f + (size_t)((3 * 64 + ctg) * 6) * 512 + laneoff;

        f32x4 acc[4][2] = {};              // [gate][rt]
        #pragma unroll
        for (int ks = 0; ks < 6; ++ks) {
            half8 bi = *(const half8*)(bpi + (size_t)ks * 512);
            half8 bf = *(const half8*)(bpf + (size_t)ks * 512);
            half8 bo = *(const half8*)(bpo + (size_t)ks * 512);
            half8 bn = *(const half8*)(bpn + (size_t)ks * 512);
            int coff = (ks & 1) * 32 + quad * 8;
            #pragma unroll
            for (int rt = 0; rt < 2; ++rt) {
                half8 aA = *(const half8*)&Tsh[rt * 16 + l15][secIF[ks >> 1] + coff];
                half8 aB = *(const half8*)&Tsh[rt * 16 + l15][secON[ks >> 1] + coff];
                acc[0][rt] = __builtin_amdgcn_mfma_f32_16x16x32_f16(aA, bi, acc[0][rt], 0, 0, 0);
                acc[1][rt] = __builtin_amdgcn_mfma_f32_16x16x32_f16(aA, bf, acc[1][rt], 0, 0, 0);
                acc[2][rt] = __builtin_amdgcn_mfma_f32_16x16x32_f16(aB, bo, acc[2][rt], 0, 0, 0);
                acc[3][rt] = __builtin_amdgcn_mfma_f32_16x16x32_f16(aB, bn, acc[3][rt], 0, 0, 0);
            }
        }

        // epilogue: corrections from fp16 LDS x/h; c from prefetch regs
        #pragma unroll
        for (int rt = 0; rt < 2; ++rt) {
            #pragma unroll
            for (int r = 0; r < 4; ++r) {
                int rl = rt * 16 + quad * 4 + r;
                size_t off = rowbase + (size_t)rl * 1024 + k;
                float xv = (float)Xsh[rl][k];
                float hv = (float)Hsh[rl][k];
                float cvv = cpref[i & 1][rt][r];
                float pi = acc[0][rt][r] + xv * cxi + hv * chi + bbi;
                float pf = acc[1][rt][r] + xv * cxf + hv * chf + bbf;
                float po = acc[2][rt][r] + xv * cxo + hv * cho + bbo;
                float pn = acc[3][rt][r] + xv * cxn + hv * chn + bbn;
                float ig = __builtin_amdgcn_rcpf(1.f + __expf(-pi));
                float fg = __builtin_amdgcn_rcpf(1.f + __expf(-pf));
                float og = __builtin_amdgcn_rcpf(1.f + __expf(-po));
                float ng = 1.f - 2.f * __builtin_amdgcn_rcpf(__expf(2.f * pn) + 1.f);
                float cn = fg * cvv + ig * ng;
                float tc = 1.f - 2.f * __builtin_amdgcn_rcpf(__expf(2.f * cn) + 1.f);
                out[off] = og * tc;
                out[(size_t)8388608 + off] = cn;
            }
        }
    }
}

// ---------------------------------------------------------------------------
extern "C" void kernel_launch(void* const* d_in, const int* in_sizes, int n_in,
                              void* d_out, int out_size, void* d_ws, size_t ws_size,
                              hipStream_t stream)
{
    const float* x      = (const float*)d_in[0];
    const float* h      = (const float*)d_in[1];
    const float* c      = (const float*)d_in[2];
    const float* dia_x  = (const float*)d_in[3];
    const float* dia_h  = (const float*)d_in[4];
    const float* Ux     = (const float*)d_in[5];
    const float* Vx     = (const float*)d_in[6];
    const float* Uh0    = (const float*)d_in[7];
    const float* Vh0    = (const float*)d_in[8];
    const float* Uh1    = (const float*)d_in[9];
    const float* Vh1    = (const float*)d_in[10];
    const float* bias_x = (const float*)d_in[11];
    const float* bias_h = (const float*)d_in[12];
    float* out = (float*)d_out;

    char* ws = (char*)d_ws;
    _Float16* U1f  = (_Float16*)(ws + WS_U1F);
    _Float16* Uh1f = (_Float16*)(ws + WS_UH1F);
    _Float16* W2f  = (_Float16*)(ws + WS_W2);
    float* cx = (float*)(ws + WS_CX);
    float* ch = (float*)(ws + WS_CH);
    float* bb = (float*)(ws + WS_BB);

    // 240 linear-section blocks + 32 Vh-transpose blocks = 272
    prep_kernel<<<272, 256, 0, stream>>>(Ux, Vx, Uh0, Vh0, Uh1, Vh1,
                                         dia_x, dia_h, bias_x, bias_h,
                                         U1f, Uh1f, W2f, cx, ch, bb);
    fused_kernel<<<256, 1024, 0, stream>>>(x, h, c, U1f, Uh1f, W2f,
                                           cx, ch, bb, out);
}